// Round 11
// baseline (2733.245 us; speedup 1.0000x reference)
//
#include <hip/hip_runtime.h>

// Pool_FPS: furthest point sampling (B=8, N=32768, K=1024) + gather (C=128).
// Single cooperative kernel: FPS + fused gather.
//
// ROUND-10 LESSON: 4-deep polling + smaller blocks barely helped -> detect
// granularity was NOT the bottleneck. Budget analysis: ~4700cy/iter of sync
// vs ~1700cy for 2 clean IF round trips. Culprit: all 16 slots of a batch
// (and its neighbor batch) shared 1-2 cache lines -> 8 stores + 32 poll
// loads SERIALIZED on one line at the coherence point every iteration.
// THIS ROUND:
//  (a) one 128B line per (parity,batch,worker) slot (16KB ws): publishes go
//      to 8 distinct lines; wave0's 8 poll lanes fetch 8 lines in ONE
//      instruction (full memory-level parallelism).
//  (b) winner coords ride in the slot line as 3 extra tagged u64 words
//      (sourced from a 48KB LDS coord mirror) -> no post-detect scalar
//      center fetch; winner extraction = 11 shuffles on wave0.
//  (c) gather fused into the kernel tail via per-block LDS winner history
//      (4KB) -> no second kernel, no idxbuf, no cross-block idx handoff.
// Protocol core unchanged (proven R7-R10, bit-exact): u64 [val:32|tag:10|n:15]
// parity slots, relaxed agent atomics, tag==t proves freshness, no fences;
// publish(t) may overwrite its own t-2 slot only after everyone passed
// detect(t-1) >= detect(t-2) -- single-writer race-free.
//
// Exactness: d = ((dx*dx+dy*dy)+dz*dz), rn ops, no fma contraction; argmax
// tie-break = smallest global index at every reduce level. idx[0]=0.
// Replay-safe: slots (tags) zeroed via hipMemsetAsync each launch.

#define BATCH 8
#define NPTS 32768
#define KSEL 1024
#define CFEAT 128
#define WPB 8                    // worker blocks per batch
#define LOCN (NPTS / WPB)        // 4096 points per block
#define TPB 512                  // 8 points per thread
#define PPT 8
#define NWAVE (TPB / 64)         // 8 waves

typedef unsigned long long u64;

#define AT_ST(p, v) __hip_atomic_store((p), (v), __ATOMIC_RELAXED, __HIP_MEMORY_SCOPE_AGENT)
#define AT_LD(p)    __hip_atomic_load((p), __ATOMIC_RELAXED, __HIP_MEMORY_SCOPE_AGENT)
#define TAG(v)      ((int)(((v) >> 15) & 1023))

__global__ void
__attribute__((amdgpu_flat_work_group_size(TPB, TPB)))
fps_kernel(const float* __restrict__ xyz, const float* __restrict__ feat,
           float* __restrict__ out, char* __restrict__ ws) {
    // ws: u64 slots[2][BATCH][WPB][16] -> one 128B line per (p,b,blk). 16KB.
    u64* slots = (u64*)ws;

    __shared__ float4 lx4[LOCN / 4], ly4[LOCN / 4], lz4[LOCN / 4];  // 48KB mirror
    __shared__ int    hist[KSEL];                                   // 4KB winners
    __shared__ float  swd[NWAVE];
    __shared__ int    swn[NWAVE];
    __shared__ float  scen[3];

    const int bid  = blockIdx.x;
    const int b    = bid & 7;                   // batch
    const int blk  = bid >> 3;                  // worker id within batch
    const int tid  = threadIdx.x;
    const int lane = tid & 63;
    const int wid  = tid >> 6;

    const float* Xp = xyz + (size_t)b * 3 * NPTS;
    const float* Yp = Xp + NPTS;
    const float* Zp = Xp + 2 * NPTS;
    const float4* X4 = (const float4*)Xp;
    const float4* Y4 = (const float4*)Yp;
    const float4* Z4 = (const float4*)Zp;

    // own 8 consecutive points: global idx = blk*LOCN + tid*8 + e
    const int f4 = blk * (LOCN / 4) + 2 * tid;
    const float4 xa = X4[f4], xb = X4[f4 + 1];
    const float4 ya = Y4[f4], yb = Y4[f4 + 1];
    const float4 za = Z4[f4], zb = Z4[f4 + 1];
    lx4[2 * tid] = xa; lx4[2 * tid + 1] = xb;
    ly4[2 * tid] = ya; ly4[2 * tid + 1] = yb;
    lz4[2 * tid] = za; lz4[2 * tid + 1] = zb;
    float xs[PPT] = {xa.x, xa.y, xa.z, xa.w, xb.x, xb.y, xb.z, xb.w};
    float ys[PPT] = {ya.x, ya.y, ya.z, ya.w, yb.x, yb.y, yb.z, yb.w};
    float zs[PPT] = {za.x, za.y, za.z, za.w, zb.x, zb.y, zb.z, zb.w};
    float ds[PPT];
#pragma unroll
    for (int e = 0; e < PPT; ++e) ds[e] = __builtin_inff();

    if (tid == 0) hist[0] = 0;                  // idx[0] = 0
    float cx = Xp[0], cy = Yp[0], cz = Zp[0];

    for (int t = 1; t < KSEL; ++t) {
        // ---- update ds, thread-local argmax (8 pts, all in regs) ----
        float bd = -__builtin_inff();
        int   be = 0;
#pragma unroll
        for (int e = 0; e < PPT; ++e) {
            const float dx = xs[e] - cx;
            const float dy = ys[e] - cy;
            const float dz = zs[e] - cz;
            // exact: ((dx*dx + dy*dy) + dz*dz), rn, no fma contraction
            const float d = __fadd_rn(__fadd_rn(__fmul_rn(dx, dx), __fmul_rn(dy, dy)),
                                      __fmul_rn(dz, dz));
            const float nd = fminf(ds[e], d);
            ds[e] = nd;
            const bool gt = nd > bd;        // strict > keeps smallest e
            bd = gt ? nd : bd;
            be = gt ? e : be;
        }
        int bn = tid * PPT + be;            // block-local point index (0..4095)
        // ---- wave argmax (max d, tie -> min index) ----
#pragma unroll
        for (int off = 32; off >= 1; off >>= 1) {
            const float od = __shfl_xor(bd, off);
            const int   on = __shfl_xor(bn, off);
            if (od > bd || (od == bd && on < bn)) { bd = od; bn = on; }
        }
        if (lane == 0) { swd[wid] = bd; swn[wid] = bn; }
        __syncthreads();                    // barrier #1

        if (wid == 0) {
            // ---- block reduce over 8 wave slots (dup-safe: lane&7) ----
            float rd = swd[lane & 7];
            int   rn = swn[lane & 7];
#pragma unroll
            for (int off = 4; off >= 1; off >>= 1) {
                const float od = __shfl_xor(rd, off);
                const int   on = __shfl_xor(rn, off);
                if (od > rd || (od == rd && on < rn)) { rd = od; rn = on; }
            }
            u64* base = slots + ((size_t)((t & 1) * BATCH + b)) * (WPB * 16);
            if (lane == 0) {
                const int gn = blk * LOCN + rn;          // batch-global index
                const float wx = ((const float*)lx4)[rn];
                const float wy = ((const float*)ly4)[rn];
                const float wz = ((const float*)lz4)[rn];
                const u64 tg = ((u64)(t & 1023) << 15);
                u64* myline = base + blk * 16;           // own 128B line
                AT_ST(myline + 0, ((u64)__float_as_uint(rd) << 32) | tg | (u64)gn);
                AT_ST(myline + 1, ((u64)__float_as_uint(wx) << 32) | tg);
                AT_ST(myline + 2, ((u64)__float_as_uint(wy) << 32) | tg);
                AT_ST(myline + 3, ((u64)__float_as_uint(wz) << 32) | tg);
            }
            // ---- poll: lane L -> word ((L>>3)&3) of block (L&7); 8 lines in
            //      parallel per load instruction; 4-deep pipelined ----
            u64* sp = base + (lane & 7) * 16 + ((lane >> 3) & 3);
            u64 v;
            for (;;) {
                const u64 v0 = AT_LD(sp);
                const u64 v1 = AT_LD(sp);
                const u64 v2 = AT_LD(sp);
                const u64 v3 = AT_LD(sp);
                if (__all(TAG(v0) == t)) { v = v0; break; }
                if (__all(TAG(v1) == t)) { v = v1; break; }
                if (__all(TAG(v2) == t)) { v = v2; break; }
                if (__all(TAG(v3) == t)) { v = v3; break; }
            }
            // ---- winner among 8 blocks (word0 lives in lanes 0..7) ----
            float bdv = -__builtin_inff();
            int   bnv = 0x7FFFFFFF;
            int   wsel = 0;
#pragma unroll
            for (int k = 0; k < 8; ++k) {
                const u64 vk = __shfl(v, k);
                const float dk = __uint_as_float((unsigned)(vk >> 32));
                const int   nk = (int)(vk & 32767);
                const bool better = (dk > bdv) || (dk == bdv && nk < bnv);
                bdv  = better ? dk : bdv;
                bnv  = better ? nk : bnv;
                wsel = better ? k : wsel;
            }
            const u64 vx = __shfl(v, 8 + wsel);    // word1 of winner block
            const u64 vy = __shfl(v, 16 + wsel);   // word2
            const u64 vz = __shfl(v, 24 + wsel);   // word3
            if (lane == 0) {
                scen[0] = __uint_as_float((unsigned)(vx >> 32));
                scen[1] = __uint_as_float((unsigned)(vy >> 32));
                scen[2] = __uint_as_float((unsigned)(vz >> 32));
                hist[t] = bnv;
            }
        }
        __syncthreads();                    // barrier #2
        cx = scen[0]; cy = scen[1]; cz = scen[2];
    }
    __syncthreads();                        // hist complete

    // ---- fused gather: block (b,blk) handles k in [blk*128, blk*128+128) ----
    const float* Fp = feat + (size_t)b * CFEAT * NPTS;
    float* outS = out + (size_t)b * 3 * KSEL;
    float* outF = out + (size_t)BATCH * 3 * KSEL + (size_t)b * CFEAT * KSEL;
    const int KPB = KSEL / WPB;             // 128
    const int k0 = blk * KPB;
    if (tid < 3 * KPB) {                    // node_static: 384 elems
        const int c = tid >> 7, kk = tid & 127;
        const int k = k0 + kk;
        const int n = hist[k];
        outS[(size_t)c * KSEL + k] = Xp[(size_t)c * NPTS + n];
    }
#pragma unroll 4
    for (int i = 0; i < (CFEAT * KPB) / TPB; ++i) {   // 32 iters
        const int linear = i * TPB + tid;
        const int c = linear >> 7;          // 0..127
        const int kk = linear & 127;
        const int k = k0 + kk;
        const int n = hist[k];
        outF[(size_t)c * KSEL + k] = Fp[(size_t)c * NPTS + n];
    }
}

extern "C" void kernel_launch(void* const* d_in, const int* in_sizes, int n_in,
                              void* d_out, int out_size, void* d_ws, size_t ws_size,
                              hipStream_t stream) {
    const float* xyz  = (const float*)d_in[0];
    const float* feat = (const float*)d_in[1];
    float* out = (float*)d_out;
    char* ws = (char*)d_ws;

    // zero slot tags every call (tag 0 never matches t>=1) — replay-safe
    hipMemsetAsync(ws, 0, 2 * BATCH * WPB * 16 * sizeof(u64), stream);

    void* args[] = {(void*)&xyz, (void*)&feat, (void*)&out, (void*)&ws};
    hipLaunchCooperativeKernel((const void*)fps_kernel,
                               dim3(BATCH * WPB), dim3(TPB), args, 0, stream);
}

// Round 12
// 2650.666 us; speedup vs baseline: 1.0312x; 1.0312x over previous
//
#include <hip/hip_runtime.h>

// Pool_FPS: furthest point sampling (B=8, N=32768, K=1024) + gather (C=128).
//
// ROUND-11 LESSONS: (1) slot line-spreading didn't speed the loop -> the
// ~2us/iter is the agent(sc1)-to-LLC store-visible + poll round trip itself.
// (2) fused gather tail with 64 blocks = latency-bound (-450us); separate
// 4192-block gather kernel is ~100us. REVERTED fusion.
// THIS ROUND: hybrid dual-path rendezvous (deadlock-PROOF, unlike R8):
//   writer: each slot word stored TWICE - workgroup-scope relaxed store
//     (write-through L1 -> lands in writer's XCD L2) then agent-scope store
//     (punches to LLC). Same payload; any observed copy is valid (tag-checked).
//   poller: alternates sc0 load (bypass L1, read LOCAL XCD L2) with agent
//     load (LLC). Same-XCD placement (coop round-robin: bids = b mod 8 land
//     together) -> sc0 sees the wg-store in ~200-300cy. If placement/sc0
//     semantics fail -> agent pair completes exactly like R10. No spin path
//     depends on unverified semantics alone.
// Kept from R11: one 128B line per (parity,batch,worker); winner coords ride
// in the slot line (words 1-3, tagged) -> no post-detect center fetch.
// Protocol core (proven bit-exact R7-R11): u64 [val:32|tag:10|n:15] parity
// slots, tag==t proves freshness, no fences needed.
//
// Exactness: d = ((dx*dx+dy*dy)+dz*dz), rn ops, no fma contraction; argmax
// tie-break = smallest global index at every reduce level. idx[0]=0.
// Replay-safe: slot tags zeroed via hipMemsetAsync each launch.

#define BATCH 8
#define NPTS 32768
#define KSEL 1024
#define CFEAT 128
#define WPB 8                    // worker blocks per batch
#define LOCN (NPTS / WPB)        // 4096 points per block
#define TPB 512                  // 8 points per thread
#define PPT 8
#define NWAVE (TPB / 64)         // 8 waves

typedef unsigned long long u64;

#define AT_ST(p, v) __hip_atomic_store((p), (v), __ATOMIC_RELAXED, __HIP_MEMORY_SCOPE_AGENT)
#define AT_LD(p)    __hip_atomic_load((p), __ATOMIC_RELAXED, __HIP_MEMORY_SCOPE_AGENT)
#define WG_ST(p, v) __hip_atomic_store((p), (v), __ATOMIC_RELAXED, __HIP_MEMORY_SCOPE_WORKGROUP)
#define TAG(v)      ((int)(((v) >> 15) & 1023))

// sc0 load: bypass L1, read this XCD's L2 (old 'glc'). Only used as the FAST
// probe of the hybrid poll - never the sole exit path (R8 lesson).
__device__ __forceinline__ u64 ld_sc0(const u64* p) {
    u64 v;
    asm volatile("global_load_dwordx2 %0, %1, off sc0\n\ts_waitcnt vmcnt(0)"
                 : "=v"(v) : "v"(p) : "memory");
    return v;
}

__global__ void
__attribute__((amdgpu_flat_work_group_size(TPB, TPB)))
fps_kernel(const float* __restrict__ xyz, char* __restrict__ ws) {
    int* idxbuf = (int*)ws;                     // [BATCH*KSEL] 32KB
    u64* slots  = (u64*)(ws + 32768);           // [2][BATCH][WPB][16] 16KB

    __shared__ float4 lx4[LOCN / 4], ly4[LOCN / 4], lz4[LOCN / 4];  // 48KB mirror
    __shared__ float  swd[NWAVE];
    __shared__ int    swn[NWAVE];
    __shared__ float  scen[3];

    const int bid  = blockIdx.x;
    const int b    = bid & 7;                   // batch
    const int blk  = bid >> 3;                  // worker id within batch
    const int tid  = threadIdx.x;
    const int lane = tid & 63;
    const int wid  = tid >> 6;

    const float* Xp = xyz + (size_t)b * 3 * NPTS;
    const float* Yp = Xp + NPTS;
    const float* Zp = Xp + 2 * NPTS;
    const float4* X4 = (const float4*)Xp;
    const float4* Y4 = (const float4*)Yp;
    const float4* Z4 = (const float4*)Zp;

    // own 8 consecutive points: global idx = blk*LOCN + tid*8 + e
    const int f4 = blk * (LOCN / 4) + 2 * tid;
    const float4 xa = X4[f4], xb = X4[f4 + 1];
    const float4 ya = Y4[f4], yb = Y4[f4 + 1];
    const float4 za = Z4[f4], zb = Z4[f4 + 1];
    lx4[2 * tid] = xa; lx4[2 * tid + 1] = xb;
    ly4[2 * tid] = ya; ly4[2 * tid + 1] = yb;
    lz4[2 * tid] = za; lz4[2 * tid + 1] = zb;
    float xs[PPT] = {xa.x, xa.y, xa.z, xa.w, xb.x, xb.y, xb.z, xb.w};
    float ys[PPT] = {ya.x, ya.y, ya.z, ya.w, yb.x, yb.y, yb.z, yb.w};
    float zs[PPT] = {za.x, za.y, za.z, za.w, zb.x, zb.y, zb.z, zb.w};
    float ds[PPT];
#pragma unroll
    for (int e = 0; e < PPT; ++e) ds[e] = __builtin_inff();

    if (blk == 0 && tid == 0) idxbuf[(size_t)b * KSEL] = 0;   // idx[0] = 0
    float cx = Xp[0], cy = Yp[0], cz = Zp[0];
    __syncthreads();   // lx4/ly4/lz4 mirror complete

    for (int t = 1; t < KSEL; ++t) {
        // ---- update ds, thread-local argmax (8 pts, all in regs) ----
        float bd = -__builtin_inff();
        int   be = 0;
#pragma unroll
        for (int e = 0; e < PPT; ++e) {
            const float dx = xs[e] - cx;
            const float dy = ys[e] - cy;
            const float dz = zs[e] - cz;
            // exact: ((dx*dx + dy*dy) + dz*dz), rn, no fma contraction
            const float d = __fadd_rn(__fadd_rn(__fmul_rn(dx, dx), __fmul_rn(dy, dy)),
                                      __fmul_rn(dz, dz));
            const float nd = fminf(ds[e], d);
            ds[e] = nd;
            const bool gt = nd > bd;        // strict > keeps smallest e
            bd = gt ? nd : bd;
            be = gt ? e : be;
        }
        int bn = tid * PPT + be;            // block-local point index (0..4095)
        // ---- wave argmax (max d, tie -> min index) ----
#pragma unroll
        for (int off = 32; off >= 1; off >>= 1) {
            const float od = __shfl_xor(bd, off);
            const int   on = __shfl_xor(bn, off);
            if (od > bd || (od == bd && on < bn)) { bd = od; bn = on; }
        }
        if (lane == 0) { swd[wid] = bd; swn[wid] = bn; }
        __syncthreads();                    // barrier #1

        if (wid == 0) {
            // ---- block reduce over 8 wave slots (dup-safe: lane&7) ----
            float rd = swd[lane & 7];
            int   rn = swn[lane & 7];
#pragma unroll
            for (int off = 4; off >= 1; off >>= 1) {
                const float od = __shfl_xor(rd, off);
                const int   on = __shfl_xor(rn, off);
                if (od > rd || (od == rd && on < rn)) { rd = od; rn = on; }
            }
            u64* base = slots + ((size_t)((t & 1) * BATCH + b)) * (WPB * 16);
            if (lane == 0) {
                const int gn = blk * LOCN + rn;          // batch-global index
                const float wx = ((const float*)lx4)[rn];
                const float wy = ((const float*)ly4)[rn];
                const float wz = ((const float*)lz4)[rn];
                const u64 tg = ((u64)(t & 1023) << 15);
                const u64 w0 = ((u64)__float_as_uint(rd) << 32) | tg | (u64)gn;
                const u64 w1 = ((u64)__float_as_uint(wx) << 32) | tg;
                const u64 w2 = ((u64)__float_as_uint(wy) << 32) | tg;
                const u64 w3 = ((u64)__float_as_uint(wz) << 32) | tg;
                u64* myline = base + blk * 16;           // own 128B line
                // dual publish: local-XCD-L2 copy (fast), then LLC copy (sure)
                WG_ST(myline + 0, w0); WG_ST(myline + 1, w1);
                WG_ST(myline + 2, w2); WG_ST(myline + 3, w3);
                AT_ST(myline + 0, w0); AT_ST(myline + 1, w1);
                AT_ST(myline + 2, w2); AT_ST(myline + 3, w3);
            }
            // ---- hybrid poll: lane L -> word ((L>>3)&3) of block (L&7);
            //      sc0 probe (local L2) alternated with agent load (LLC) ----
            u64* sp = base + (lane & 7) * 16 + ((lane >> 3) & 3);
            u64 v;
            for (;;) {
                const u64 vf = ld_sc0(sp);
                if (__all(TAG(vf) == t)) { v = vf; break; }
                const u64 va = AT_LD(sp);
                if (__all(TAG(va) == t)) { v = va; break; }
            }
            // ---- winner among 8 blocks (word0 lives in lanes 0..7) ----
            float bdv = -__builtin_inff();
            int   bnv = 0x7FFFFFFF;
            int   wsel = 0;
#pragma unroll
            for (int k = 0; k < 8; ++k) {
                const u64 vk = __shfl(v, k);
                const float dk = __uint_as_float((unsigned)(vk >> 32));
                const int   nk = (int)(vk & 32767);
                const bool better = (dk > bdv) || (dk == bdv && nk < bnv);
                bdv  = better ? dk : bdv;
                bnv  = better ? nk : bnv;
                wsel = better ? k : wsel;
            }
            const u64 vx = __shfl(v, 8 + wsel);    // word1 of winner block
            const u64 vy = __shfl(v, 16 + wsel);   // word2
            const u64 vz = __shfl(v, 24 + wsel);   // word3
            if (lane == 0) {
                scen[0] = __uint_as_float((unsigned)(vx >> 32));
                scen[1] = __uint_as_float((unsigned)(vy >> 32));
                scen[2] = __uint_as_float((unsigned)(vz >> 32));
                if (blk == 0) idxbuf[(size_t)b * KSEL + t] = bnv;
            }
        }
        __syncthreads();                    // barrier #2
        cx = scen[0]; cy = scen[1]; cz = scen[2];
    }
}

__global__ void gather_kernel(const float* __restrict__ xyz,
                              const float* __restrict__ feat,
                              const int* __restrict__ idxbuf,
                              float* __restrict__ out) {
    const int SN = BATCH * 3 * KSEL;                  // 24576
    const int total = SN + BATCH * CFEAT * KSEL;      // 1073152
    const int i = blockIdx.x * blockDim.x + threadIdx.x;
    if (i >= total) return;
    if (i < SN) {
        const int b = i / (3 * KSEL);
        const int r = i - b * 3 * KSEL;
        const int c = r / KSEL;
        const int k = r - c * KSEL;
        const int n = idxbuf[b * KSEL + k];
        out[i] = xyz[((size_t)b * 3 + c) * NPTS + n];
    } else {
        const int i2 = i - SN;
        const int b = i2 / (CFEAT * KSEL);
        const int r = i2 - b * CFEAT * KSEL;
        const int c = r / KSEL;
        const int k = r - c * KSEL;
        const int n = idxbuf[b * KSEL + k];
        out[SN + i2] = feat[((size_t)b * CFEAT + c) * NPTS + n];
    }
}

extern "C" void kernel_launch(void* const* d_in, const int* in_sizes, int n_in,
                              void* d_out, int out_size, void* d_ws, size_t ws_size,
                              hipStream_t stream) {
    const float* xyz  = (const float*)d_in[0];
    const float* feat = (const float*)d_in[1];
    float* out = (float*)d_out;
    char* ws = (char*)d_ws;
    // ws layout: [0,32KB) idxbuf | [32KB, +16KB) u64 slots [2][8][8][16]

    // zero slot tags every call (tag 0 never matches t>=1) — replay-safe
    hipMemsetAsync(ws + 32768, 0, 2 * BATCH * WPB * 16 * sizeof(u64), stream);

    void* args[] = {(void*)&xyz, (void*)&ws};
    hipLaunchCooperativeKernel((const void*)fps_kernel,
                               dim3(BATCH * WPB), dim3(TPB), args, 0, stream);

    int* idxbuf = (int*)d_ws;
    const int total = BATCH * 3 * KSEL + BATCH * CFEAT * KSEL;  // 1073152
    gather_kernel<<<(total + 255) / 256, 256, 0, stream>>>(xyz, feat, idxbuf, out);
}